// Round 2
// baseline (123.551 us; speedup 1.0000x reference)
//
#include <hip/hip_runtime.h>
#include <math.h>

#define N 4096
#define B 2048
#define RANK 4
#define ALPHA 0.8862269254527580f   // sqrt(pi)/2
#define INV_N (1.0f / 4096.0f)

#define SPLITS 256
#define RPB (N / SPLITS)            // 16 rows per block in kernel 1
#define R3 16                       // rows per block in kernel 3

// ---------------------------------------------------------------------------
// Kernel 1: partial rank-4 (+z) reduction over row-splits.
// grid (B/1024, SPLITS), block 256. Block = 1024 cols (float4/thread) x RPB rows.
// Full unroll -> 16 independent float4 loads in flight per thread (16 KB/wave);
// 512 blocks -> 2 blocks/CU, 8 waves/CU. Latency-hiding fix for R0's 451 GB/s.
// v/z rows staged in LDS (wave-uniform reads -> broadcast, conflict-free).
// ---------------------------------------------------------------------------
__global__ __launch_bounds__(256) void k_reduce_partial(
    const float* __restrict__ h, const float* __restrict__ v,
    const float* __restrict__ z, float* __restrict__ partials) {
  __shared__ float lv[RPB * RANK];  // 64 floats, v rows are contiguous
  __shared__ float lz[RPB];
  const int tid = threadIdx.x;
  const int b4 = blockIdx.x * 1024 + tid * 4;
  const int row0 = blockIdx.y * RPB;

  if (tid < RPB * RANK) lv[tid] = v[row0 * RANK + tid];
  if (tid >= 64 && tid < 64 + RPB) lz[tid - 64] = z[row0 + (tid - 64)];
  __syncthreads();

  float4 a0 = {0.f, 0.f, 0.f, 0.f}, a1 = a0, a2 = a0, a3 = a0, az = a0;
  const float* hp = h + (size_t)row0 * B + b4;
#pragma unroll
  for (int i = 0; i < RPB; ++i) {
    const float4 hv = *(const float4*)(hp + (size_t)i * B);
    float4 p;
    p.x = erff(ALPHA * hv.x);
    p.y = erff(ALPHA * hv.y);
    p.z = erff(ALPHA * hv.z);
    p.w = erff(ALPHA * hv.w);
    const float v0 = lv[i * 4 + 0], v1 = lv[i * 4 + 1];
    const float v2 = lv[i * 4 + 2], v3 = lv[i * 4 + 3];
    const float zi = lz[i];
    a0.x = fmaf(v0, p.x, a0.x); a0.y = fmaf(v0, p.y, a0.y);
    a0.z = fmaf(v0, p.z, a0.z); a0.w = fmaf(v0, p.w, a0.w);
    a1.x = fmaf(v1, p.x, a1.x); a1.y = fmaf(v1, p.y, a1.y);
    a1.z = fmaf(v1, p.z, a1.z); a1.w = fmaf(v1, p.w, a1.w);
    a2.x = fmaf(v2, p.x, a2.x); a2.y = fmaf(v2, p.y, a2.y);
    a2.z = fmaf(v2, p.z, a2.z); a2.w = fmaf(v2, p.w, a2.w);
    a3.x = fmaf(v3, p.x, a3.x); a3.y = fmaf(v3, p.y, a3.y);
    a3.z = fmaf(v3, p.z, a3.z); a3.w = fmaf(v3, p.w, a3.w);
    az.x = fmaf(zi, p.x, az.x); az.y = fmaf(zi, p.y, az.y);
    az.z = fmaf(zi, p.z, az.z); az.w = fmaf(zi, p.w, az.w);
  }

  float* pp = partials + (size_t)blockIdx.y * 5 * B + b4;
  *(float4*)(pp + 0 * B) = a0;
  *(float4*)(pp + 1 * B) = a1;
  *(float4*)(pp + 2 * B) = a2;
  *(float4*)(pp + 3 * B) = a3;
  *(float4*)(pp + 4 * B) = az;
}

// ---------------------------------------------------------------------------
// Kernel 2: sum the SPLITS partials -> final s[4][B] (ws) and y[B] (d_out).
// 5*B outputs, one thread each; coalesced along b within each split row.
// Partials (10.5 MB) are L2/L3-resident; unroll gives independent loads.
// ---------------------------------------------------------------------------
__global__ __launch_bounds__(256) void k_reduce_final(
    const float* __restrict__ partials, float* __restrict__ sfin,
    float* __restrict__ y) {
  const int o = blockIdx.x * 256 + threadIdx.x;  // [0, 5*B)
  const int r = o / B;
  const int b = o - r * B;
  float s = 0.f;
#pragma unroll 16
  for (int sp = 0; sp < SPLITS; ++sp)
    s += partials[((size_t)sp * 5 + r) * B + b];
  if (r < RANK)
    sfin[(size_t)r * B + b] = s;
  else
    y[b] = s * INV_N;  // y = (z.T @ phi) / N ; 1/4096 is exact
}

// ---------------------------------------------------------------------------
// Kernel 3: h_new[n][b] = (sum_r u[n][r]*s[r][b]) / N + m[n]*x[b]
// (DT/TAU = 1 makes h cancel exactly -- h is never read here.)
// grid (B/1024, N/R3), block 256; thread owns 4 consecutive cols (float4).
// s/x hoisted out of the row loop; u/m are block-uniform scalar loads.
// Pure coalesced float4 write stream of 33.5 MB.
// ---------------------------------------------------------------------------
__global__ __launch_bounds__(256) void k_update(
    const float* __restrict__ sfin, const float* __restrict__ u,
    const float* __restrict__ m, const float* __restrict__ x,
    float* __restrict__ hnew) {
  const int b4 = (blockIdx.x * 256 + threadIdx.x) * 4;
  const int row0 = blockIdx.y * R3;

  const float4 s0 = *(const float4*)(sfin + 0 * B + b4);
  const float4 s1 = *(const float4*)(sfin + 1 * B + b4);
  const float4 s2 = *(const float4*)(sfin + 2 * B + b4);
  const float4 s3 = *(const float4*)(sfin + 3 * B + b4);
  const float4 xv = *(const float4*)(x + b4);

#pragma unroll
  for (int i = 0; i < R3; ++i) {
    const int n = row0 + i;
    const float4 uv = *(const float4*)(u + (size_t)n * RANK);
    const float mv = m[n];
    float4 o;
    o.x = fmaf(mv, xv.x,
               (s0.x * uv.x + s1.x * uv.y + s2.x * uv.z + s3.x * uv.w) * INV_N);
    o.y = fmaf(mv, xv.y,
               (s0.y * uv.x + s1.y * uv.y + s2.y * uv.z + s3.y * uv.w) * INV_N);
    o.z = fmaf(mv, xv.z,
               (s0.z * uv.x + s1.z * uv.y + s2.z * uv.z + s3.z * uv.w) * INV_N);
    o.w = fmaf(mv, xv.w,
               (s0.w * uv.x + s1.w * uv.y + s2.w * uv.z + s3.w * uv.w) * INV_N);
    *(float4*)(hnew + (size_t)n * B + b4) = o;
  }
}

// ---------------------------------------------------------------------------
extern "C" void kernel_launch(void* const* d_in, const int* in_sizes, int n_in,
                              void* d_out, int out_size, void* d_ws,
                              size_t ws_size, hipStream_t stream) {
  const float* x = (const float*)d_in[0];  // [1, B]
  const float* h = (const float*)d_in[1];  // [N, B]
  const float* m = (const float*)d_in[2];  // [N, 1]
  const float* u = (const float*)d_in[3];  // [N, RANK]
  const float* v = (const float*)d_in[4];  // [N, RANK]
  const float* z = (const float*)d_in[5];  // [N, 1]

  float* y = (float*)d_out;            // first output: y [1, B]
  float* hnew = (float*)d_out + B;     // second output: h_new [N, B]

  float* partials = (float*)d_ws;                        // [SPLITS][5][B]
  float* sfin = (float*)d_ws + (size_t)SPLITS * 5 * B;   // [RANK][B]
  // ws usage: (256*5*2048 + 4*2048) * 4 B = ~10.5 MB

  k_reduce_partial<<<dim3(B / 1024, SPLITS), 256, 0, stream>>>(h, v, z,
                                                               partials);
  k_reduce_final<<<(5 * B) / 256, 256, 0, stream>>>(partials, sfin, y);
  k_update<<<dim3(B / 1024, N / R3), 256, 0, stream>>>(sfin, u, m, x, hnew);
}